// Round 1
// baseline (662.086 us; speedup 1.0000x reference)
//
#include <hip/hip_runtime.h>
#include <hip/hip_bf16.h>

#define L_LAYERS 16
#define H_DIM    128
#define X_IN_    47508
#define X_TOT_   47764
#define K_TOT_   47636   // X_IN + H (static part of K)
#define BS_      128
#define V_T_     3620
#define NCHUNK   8
#define KCHUNK   5952    // 93*64; last chunk = 47636-7*5952 = 5972 (94 tiles, guarded)
#define G4_      512

typedef __attribute__((ext_vector_type(8))) short bf16x8;
typedef __attribute__((ext_vector_type(4))) float f32x4;

__device__ __forceinline__ unsigned short f2bf(float f) {
    union { __hip_bfloat16 h; unsigned short u; } cv;
    cv.h = __float2bfloat16(f);
    return cv.u;
}

// ---------------------------------------------------------------------------
// Kernel 1: g_static[l][b][4H] = [input_x, prev_hidden[:,l]] @ W_gate[l][0:47636]
// grid = 64 layer-gates * 8 K-chunks; blockIdx = lg*8 + s  (chunk -> XCD)
// Per block: 128x128 output tile, K-loop in 64-steps, bf16 MFMA 16x16x32.
// A (z rows) staged in LDS (bf16, XOR-swizzled); B (W) direct global->frag.
// ---------------------------------------------------------------------------
__global__ __launch_bounds__(256, 2)
void gemm_static_kernel(const float* __restrict__ input_x,
                        const float* __restrict__ prev_hidden,
                        const float* __restrict__ Wi,
                        const float* __restrict__ Wf,
                        const float* __restrict__ Ws,
                        const float* __restrict__ Wo,
                        float* __restrict__ partials)
{
    const int bid   = blockIdx.x;
    const int s     = bid & (NCHUNK - 1);
    const int lg    = bid >> 3;
    const int layer = lg >> 2;
    const int gate  = lg & 3;
    const float* W;
    if      (gate == 0) W = Wi;
    else if (gate == 1) W = Wf;
    else if (gate == 2) W = Ws;
    else                W = Wo;
    W += (size_t)layer * X_TOT_ * H_DIM;

    const int k_begin = s * KCHUNK;
    const int k_end   = (s == NCHUNK - 1) ? K_TOT_ : (k_begin + KCHUNK);
    const int NT      = (k_end - k_begin + 63) >> 6;

    const int tid  = threadIdx.x;
    const int lane = tid & 63;
    const int wv   = tid >> 6;     // wave 0..3 -> N cols [wv*32, wv*32+32)
    const int l15  = lane & 15;
    const int lg4  = lane >> 4;
    const int ar   = tid >> 4;     // A staging base row 0..15
    const int ac4  = tid & 15;     // A staging 16B column

    __shared__ unsigned short A_lds[128 * 64];   // bf16 [row][k], 16B-chunk XOR swizzle

    f32x4 acc[8][2];
    {
        f32x4 z = {0.f, 0.f, 0.f, 0.f};
        #pragma unroll
        for (int i = 0; i < 8; ++i)
            #pragma unroll
            for (int j = 0; j < 2; ++j)
                acc[i][j] = z;
    }

    float4 aq[8];   // A staging regs (tile t fp32)
    float  bq[32];  // B staging regs (tile t fp32)

    auto loadA = [&](int t) {
        const int k0 = k_begin + (t << 6);
        const int kk = k0 + ac4 * 4;
        if (k0 + 64 <= X_IN_) {
            #pragma unroll
            for (int rep = 0; rep < 8; ++rep) {
                const int r = rep * 16 + ar;
                aq[rep] = *reinterpret_cast<const float4*>(input_x + (size_t)r * X_IN_ + kk);
            }
        } else {
            #pragma unroll
            for (int rep = 0; rep < 8; ++rep) {
                const int r = rep * 16 + ar;
                float v[4];
                #pragma unroll
                for (int j = 0; j < 4; ++j) {
                    const int k = kk + j;
                    float x = 0.f;
                    if (k < X_IN_)
                        x = input_x[(size_t)r * X_IN_ + k];
                    else if (k < K_TOT_)
                        x = prev_hidden[((size_t)r * L_LAYERS + layer) * H_DIM + (k - X_IN_)];
                    v[j] = x;
                }
                aq[rep] = make_float4(v[0], v[1], v[2], v[3]);
            }
        }
    };

    auto loadB = [&](int t) {
        const int k0 = k_begin + (t << 6);
        const bool full = (k0 + 64 <= k_end);
        #pragma unroll
        for (int ks = 0; ks < 2; ++ks)
            #pragma unroll
            for (int ni = 0; ni < 2; ++ni) {
                const int c  = wv * 32 + ni * 16 + l15;
                const int kb = k0 + ks * 32 + lg4 * 8;
                const float* p = W + (size_t)kb * H_DIM + c;
                if (full) {
                    #pragma unroll
                    for (int j = 0; j < 8; ++j)
                        bq[(ks * 2 + ni) * 8 + j] = p[(size_t)j * H_DIM];
                } else {
                    #pragma unroll
                    for (int j = 0; j < 8; ++j)
                        bq[(ks * 2 + ni) * 8 + j] = (kb + j < k_end) ? p[(size_t)j * H_DIM] : 0.f;
                }
            }
    };

    auto writeA = [&]() {
        #pragma unroll
        for (int rep = 0; rep < 8; ++rep) {
            const int r = rep * 16 + ar;
            uint2 pk;
            pk.x = (unsigned)f2bf(aq[rep].x) | ((unsigned)f2bf(aq[rep].y) << 16);
            pk.y = (unsigned)f2bf(aq[rep].z) | ((unsigned)f2bf(aq[rep].w) << 16);
            const int c8  = ac4 >> 1;
            const int off = r * 128 + ((c8 ^ (r & 7)) << 4) + ((ac4 & 1) << 3);
            *reinterpret_cast<uint2*>(reinterpret_cast<char*>(A_lds) + off) = pk;
        }
    };

    bf16x8 bfrag[2][2];
    auto cvtB = [&]() {
        #pragma unroll
        for (int f = 0; f < 4; ++f) {
            bf16x8 v;
            #pragma unroll
            for (int j = 0; j < 8; ++j)
                v[j] = (short)f2bf(bq[f * 8 + j]);
            bfrag[f >> 1][f & 1] = v;
        }
    };

    auto mma = [&]() {
        #pragma unroll
        for (int ks = 0; ks < 2; ++ks) {
            #pragma unroll
            for (int mi = 0; mi < 8; ++mi) {
                const int r   = mi * 16 + l15;
                const int off = r * 128 + (((ks * 4 + lg4) ^ (l15 & 7)) << 4);
                const bf16x8 a = *reinterpret_cast<const bf16x8*>(
                    reinterpret_cast<const char*>(A_lds) + off);
                acc[mi][0] = __builtin_amdgcn_mfma_f32_16x16x32_bf16(a, bfrag[ks][0], acc[mi][0], 0, 0, 0);
                acc[mi][1] = __builtin_amdgcn_mfma_f32_16x16x32_bf16(a, bfrag[ks][1], acc[mi][1], 0, 0, 0);
            }
        }
    };

    loadA(0);
    loadB(0);
    for (int t = 0; t < NT; ++t) {
        __syncthreads();          // previous MFMA phase done reading A_lds
        writeA();                 // waits A loads (tile t), converts, stages
        cvtB();                   // waits B loads (tile t) -> fragments
        if (t + 1 < NT) { loadA(t + 1); loadB(t + 1); }  // prefetch overlaps MFMA
        __syncthreads();          // A_lds ready
        mma();
    }

    // Store partials[((s*L + layer)*BS + r)*512 + gate*128 + c]
    float* outp = partials + (size_t)(s * L_LAYERS + layer) * BS_ * G4_;
    #pragma unroll
    for (int mi = 0; mi < 8; ++mi)
        #pragma unroll
        for (int ni = 0; ni < 2; ++ni)
            #pragma unroll
            for (int rg = 0; rg < 4; ++rg) {
                const int r = mi * 16 + lg4 * 4 + rg;
                const int c = wv * 32 + ni * 16 + l15;
                outp[(size_t)r * G4_ + gate * 128 + c] = acc[mi][ni][rg];
            }
}

// ---------------------------------------------------------------------------
// Kernel 2: sequential tail. One block per batch row (dependency is per-row).
// For each layer: g = sum_s partials + bias + prev_hidden_layer @ W_prevslice,
// gates -> new_hidden -> flat_hidden; prev kept in LDS.
// ---------------------------------------------------------------------------
__global__ __launch_bounds__(512)
void lstm_tail_kernel(const float* __restrict__ partials,
                      const float* __restrict__ Wi, const float* __restrict__ Wf,
                      const float* __restrict__ Ws, const float* __restrict__ Wo,
                      const float* __restrict__ bi, const float* __restrict__ bfv,
                      const float* __restrict__ bs, const float* __restrict__ bo,
                      const float* __restrict__ old_states,
                      float* __restrict__ flat_hidden)
{
    const int b    = blockIdx.x;
    const int n    = threadIdx.x;   // 0..511
    const int gate = n >> 7;
    const int c    = n & 127;
    __shared__ float prev[H_DIM];
    __shared__ float gbuf[G4_];
    const float* Wsel = (gate == 0) ? Wi : (gate == 1) ? Wf : (gate == 2) ? Ws : Wo;
    const float* bsel = (gate == 0) ? bi : (gate == 1) ? bfv : (gate == 2) ? bs : bo;

    for (int i = 0; i < L_LAYERS; ++i) {
        float acc = bsel[i * H_DIM + c];
        #pragma unroll
        for (int s2 = 0; s2 < NCHUNK; ++s2)
            acc += partials[((size_t)(s2 * L_LAYERS + i) * BS_ + b) * G4_ + n];
        if (i > 0) {
            const float* Wp = Wsel + ((size_t)i * X_TOT_ + X_IN_ + H_DIM) * H_DIM + c;
            #pragma unroll 4
            for (int h = 0; h < H_DIM; ++h)
                acc += prev[h] * Wp[(size_t)h * H_DIM];
        }
        gbuf[n] = acc;
        __syncthreads();
        if (n < H_DIM) {
            const float ig = 1.f / (1.f + expf(-gbuf[n]));
            const float fg = 1.f / (1.f + expf(-gbuf[128 + n]));
            const float sg = tanhf(gbuf[256 + n]);
            const float og = 1.f / (1.f + expf(-gbuf[384 + n]));
            const float st = fg * old_states[((size_t)i * BS_ + b) * H_DIM + n] + ig * sg;
            const float nh = og * tanhf(st);
            flat_hidden[(size_t)b * (L_LAYERS * H_DIM) + i * H_DIM + n] = nh;
            prev[n] = nh;
        }
        __syncthreads();
    }
}

// ---------------------------------------------------------------------------
// Kernel 3: out[128][3620] = flat_hidden[128][2048] @ Wy[2048][3620], bf16 MFMA.
// Block = 128M x 32N (4 waves of 32M x 32N). No LDS; caches dedupe A.
// ---------------------------------------------------------------------------
__global__ __launch_bounds__(256, 2)
void gemm_out_kernel(const float* __restrict__ flat_hidden,
                     const float* __restrict__ Wy,
                     float* __restrict__ out)
{
    const int tid  = threadIdx.x;
    const int lane = tid & 63;
    const int wv   = tid >> 6;
    const int l15  = lane & 15;
    const int lg4  = lane >> 4;
    const int n0   = blockIdx.x * 32;
    const int m0   = wv * 32;

    f32x4 acc[2][2];
    {
        f32x4 z = {0.f, 0.f, 0.f, 0.f};
        #pragma unroll
        for (int i = 0; i < 2; ++i)
            #pragma unroll
            for (int j = 0; j < 2; ++j)
                acc[i][j] = z;
    }

    for (int kt = 0; kt < 64; ++kt) {
        const int k0 = kt * 32 + lg4 * 8;
        bf16x8 afr[2], bfr[2];
        #pragma unroll
        for (int mi = 0; mi < 2; ++mi) {
            const float* ap = flat_hidden + (size_t)(m0 + mi * 16 + l15) * (L_LAYERS * H_DIM) + k0;
            const float4 a0 = *reinterpret_cast<const float4*>(ap);
            const float4 a1 = *reinterpret_cast<const float4*>(ap + 4);
            bf16x8 v;
            v[0] = (short)f2bf(a0.x); v[1] = (short)f2bf(a0.y);
            v[2] = (short)f2bf(a0.z); v[3] = (short)f2bf(a0.w);
            v[4] = (short)f2bf(a1.x); v[5] = (short)f2bf(a1.y);
            v[6] = (short)f2bf(a1.z); v[7] = (short)f2bf(a1.w);
            afr[mi] = v;
        }
        #pragma unroll
        for (int ni = 0; ni < 2; ++ni) {
            const int c = n0 + ni * 16 + l15;
            bf16x8 v;
            if (c < V_T_) {
                const float* bp = Wy + (size_t)k0 * V_T_ + c;
                #pragma unroll
                for (int j = 0; j < 8; ++j)
                    v[j] = (short)f2bf(bp[(size_t)j * V_T_]);
            } else {
                #pragma unroll
                for (int j = 0; j < 8; ++j) v[j] = 0;
            }
            bfr[ni] = v;
        }
        #pragma unroll
        for (int mi = 0; mi < 2; ++mi)
            #pragma unroll
            for (int ni = 0; ni < 2; ++ni)
                acc[mi][ni] = __builtin_amdgcn_mfma_f32_16x16x32_bf16(afr[mi], bfr[ni], acc[mi][ni], 0, 0, 0);
    }

    #pragma unroll
    for (int mi = 0; mi < 2; ++mi)
        #pragma unroll
        for (int ni = 0; ni < 2; ++ni) {
            const int c = n0 + ni * 16 + l15;
            if (c < V_T_) {
                #pragma unroll
                for (int rg = 0; rg < 4; ++rg) {
                    const int r = m0 + mi * 16 + lg4 * 4 + rg;
                    out[(size_t)r * V_T_ + c] = acc[mi][ni][rg];
                }
            }
        }
}

// ---------------------------------------------------------------------------
extern "C" void kernel_launch(void* const* d_in, const int* in_sizes, int n_in,
                              void* d_out, int out_size, void* d_ws, size_t ws_size,
                              hipStream_t stream)
{
    (void)in_sizes; (void)n_in; (void)out_size; (void)ws_size;
    const float* input_x     = (const float*)d_in[0];
    const float* prev_hidden = (const float*)d_in[1];
    const float* old_states  = (const float*)d_in[2];
    const float* Wi = (const float*)d_in[3];
    const float* bi = (const float*)d_in[4];
    const float* Wf = (const float*)d_in[5];
    const float* bfv = (const float*)d_in[6];
    const float* Wo = (const float*)d_in[7];
    const float* bo = (const float*)d_in[8];
    const float* Ws = (const float*)d_in[9];
    const float* bs = (const float*)d_in[10];
    const float* Wy = (const float*)d_in[11];
    float* out = (float*)d_out;

    float* partials    = (float*)d_ws;   // 8*16*128*512*4 = 32 MiB
    float* flat_hidden = (float*)((char*)d_ws +
                         (size_t)NCHUNK * L_LAYERS * BS_ * G4_ * sizeof(float)); // +1 MiB

    gemm_static_kernel<<<dim3(64 * NCHUNK), dim3(256), 0, stream>>>(
        input_x, prev_hidden, Wi, Wf, Ws, Wo, partials);
    lstm_tail_kernel<<<dim3(BS_), dim3(512), 0, stream>>>(
        partials, Wi, Wf, Ws, Wo, bi, bfv, bs, bo, old_states, flat_hidden);
    gemm_out_kernel<<<dim3((V_T_ + 31) / 32), dim3(256), 0, stream>>>(
        flat_hidden, Wy, out);
}